// Round 12
// baseline (209.716 us; speedup 1.0000x reference)
//
#include <hip/hip_runtime.h>

#define N_PTS 150000
#define NK 27
#define CIN 128
#define COUT 128
#define BM 128
#define NBLK ((N_PTS + BM - 1) / BM)   // 1172

typedef __attribute__((ext_vector_type(8))) short bfrag8;   // 8 bf16
typedef __attribute__((ext_vector_type(4))) float facc4;    // 4 f32

__device__ inline unsigned short f2bf(float f) {
    unsigned u = __builtin_bit_cast(unsigned, f);
    u += 0x7FFFu + ((u >> 16) & 1u);            // RNE
    return (unsigned short)(u >> 16);
}
__device__ inline unsigned pack2(float a, float b) {
    return (unsigned)f2bf(a) | ((unsigned)f2bf(b) << 16);
}
__device__ inline void glds16(const void* g, void* l) {
    __builtin_amdgcn_global_load_lds(
        (const __attribute__((address_space(1))) void*)g,
        (__attribute__((address_space(3))) void*)l, 16, 0, 0);
}

// ---- prep: fp32 data -> bf16, plus one zeroed row at index N_PTS ----
__global__ void cast_data_kernel(const float* __restrict__ in,
                                 unsigned short* __restrict__ out) {
    const int n8_data = N_PTS * (CIN / 8);
    const int n8_all  = (N_PTS + 1) * (CIN / 8);
    int i = blockIdx.x * blockDim.x + threadIdx.x;
    int stride = gridDim.x * blockDim.x;
    for (; i < n8_all; i += stride) {
        uint4 v;
        if (i < n8_data) {
            const float4* p = (const float4*)(in + (size_t)i * 8);
            float4 x = p[0], y = p[1];
            v.x = pack2(x.x, x.y); v.y = pack2(x.z, x.w);
            v.z = pack2(y.x, y.y); v.w = pack2(y.z, y.w);
        } else {
            v.x = v.y = v.z = v.w = 0u;
        }
        *(uint4*)(out + (size_t)i * 8) = v;
    }
}

// ---- prep: W[co][k][ci] -> wkh[k][h][co][bu] bf16 16B units, pre-swizzled bu^(co&7) ----
__global__ void prep_weights_h(const float* __restrict__ w,
                               unsigned short* __restrict__ wkh) {
    int i = blockIdx.x * blockDim.x + threadIdx.x;
    if (i >= NK * 2 * 128 * 8) return;
    int bu = i & 7, co = (i >> 3) & 127, h = (i >> 10) & 1, k = i >> 11;
    int ci = h * 64 + (bu ^ (co & 7)) * 8;
    const float4* src = (const float4*)(w + ((size_t)co * NK + k) * CIN + ci);
    float4 x = src[0], y = src[1];
    uint4 v;
    v.x = pack2(x.x, x.y); v.y = pack2(x.z, x.w);
    v.z = pack2(y.x, y.y); v.w = pack2(y.z, y.w);
    ((uint4*)wkh)[i] = v;
}

// ---- prep: nbr[N][27] -> nbrT[27][N] via LDS tile (coalesced both sides) ----
__global__ void transpose_nbr(const int* __restrict__ nbr, int* __restrict__ nbrT) {
    __shared__ int tile[256 * NK];
    const int t  = threadIdx.x;              // 256
    const int m0 = blockIdx.x * 256;
    const int base = m0 * NK;
    for (int i = t; i < 256 * NK; i += 256) {
        int g = base + i;
        tile[i] = (g < N_PTS * NK) ? nbr[g] : -1;
    }
    __syncthreads();
    const int row = m0 + t;
    if (row < N_PTS) {
#pragma unroll
        for (int k = 0; k < NK; ++k) nbrT[k * N_PTS + row] = tile[t * NK + k];
    }
}

// ================= main kernel (v11 = v8 pipeline at v10 occupancy) =================
// 512 threads / 8 waves, BM=128, wave = 32 rows x 64 couts. 54 phases (K=64).
// A: glds gather, TRIPLE buffer 3x16KB, staged 2 phases ahead (counted vmcnt).
// B: glds, double buffer 2x16KB, staged 1 ahead. idx: VGPR prefetch from nbrT
// (coalesced; 1 phase ahead). LDS exactly 81920 B -> 2 blocks/CU.
// Steady-state queue at barrier: [A(p+1)x2, B(p+1)x2, A(p+2)x2, ivn x2] in some
// order with {A(p+1)} oldest -> wait vmcnt(4) completes A(p+1),B(p+1).

#define LOAD_IV(G, IV0, IV1)                                                 \
  {                                                                          \
    const int kq_ = (G) >> 1;                                                \
    IV0 = nbrS[(size_t)kq_ * kStr + (size_t)r0c * rStr];                     \
    IV1 = nbrS[(size_t)kq_ * kStr + (size_t)r1c * rStr];                     \
  }

#define STAGE_A(Q, ADST, IV0, IV1)                                           \
  {                                                                          \
    const int hb_ = ((Q) & 1) << 7;                                          \
    size_t e0 = (s0ok && (IV0) >= 0) ? (size_t)(IV0) : (size_t)N_PTS;        \
    size_t e1 = (s1ok && (IV1) >= 0) ? (size_t)(IV1) : (size_t)N_PTS;        \
    glds16(dbfB + e0 * 256 + hb_ + aswz, (ADST) + s0 * 128 + lu16);          \
    glds16(dbfB + e1 * 256 + hb_ + aswz, (ADST) + s1 * 128 + lu16);          \
  }

#define STAGE_B(Q, BDST)                                                     \
  {                                                                          \
    const char* bs_ = wkhB + (size_t)(Q) * 16384 + t * 16;                   \
    glds16(bs_,        (BDST) + t * 16);                                     \
    glds16(bs_ + 8192, (BDST) + t * 16 + 8192);                              \
  }

#define MFMA_PHASE(ABUF, BBUF)                                                      \
  {                                                                                 \
    __builtin_amdgcn_s_setprio(1);                                                  \
    _Pragma("unroll")                                                               \
    for (int kk = 0; kk < 2; ++kk) {                                                \
      const int sw_ = (((kk * 4 + lk) ^ (lr & 7)) << 4);                            \
      bfrag8 a0 = *(const bfrag8*)((ABUF) + (wrow * 32 + lr) * 128 + sw_);          \
      bfrag8 a1 = *(const bfrag8*)((ABUF) + (wrow * 32 + 16 + lr) * 128 + sw_);     \
      _Pragma("unroll")                                                             \
      for (int ct = 0; ct < 4; ++ct) {                                              \
        bfrag8 b = *(const bfrag8*)((BBUF) + (h * 64 + ct * 16 + lr) * 128 + sw_);  \
        acc[0][ct] = __builtin_amdgcn_mfma_f32_16x16x32_bf16(a0, b, acc[0][ct],     \
                                                             0, 0, 0);              \
        acc[1][ct] = __builtin_amdgcn_mfma_f32_16x16x32_bf16(a1, b, acc[1][ct],     \
                                                             0, 0, 0);              \
      }                                                                             \
    }                                                                               \
    __builtin_amdgcn_s_setprio(0);                                                  \
  }

#define WAIT_BAR(N)                                                          \
    __builtin_amdgcn_sched_barrier(0);                                       \
    asm volatile("s_waitcnt vmcnt(" #N ")" ::: "memory");                    \
    __builtin_amdgcn_s_barrier();                                            \
    __builtin_amdgcn_sched_barrier(0);

#define ROTATE_BUFS                                                          \
    { char* tp = pAr; pAr = pAm; pAm = pAw; pAw = tp; }                      \
    { char* tp = pBr; pBr = pBw; pBw = tp; }

__global__ __launch_bounds__(512, 4)
void octconv_v11(const unsigned short* __restrict__ dbf,   // [N_PTS+1][128] bf16
                 const unsigned short* __restrict__ wkh,   // [27][2][128][8u] preswz
                 const int* __restrict__ nbrS,             // idx, strides (kStr,rStr)
                 const int kStr, const int rStr,
                 float* __restrict__ out) {
    // A triple 48K | B double 32K = 81920 B exactly -> 2 blocks/CU
    __shared__ __align__(1024) unsigned char lds[3 * 16384 + 2 * 16384];

    const int t = threadIdx.x;
    const int w = t >> 6, l = t & 63;
    const int lr = l & 15, lk = l >> 4;
    const int h = w & 1, wrow = w >> 1;
    const int m0 = blockIdx.x * BM;

    // A staging: thread -> slots s0=(t>>3), s0+64; units l&7 (lane-linear dest)
    const int lu   = l & 7;
    const int lu16 = lu * 16;
    const int s0 = t >> 3;
    const int s1 = s0 + 64;
    const bool s0ok = (m0 + s0) < N_PTS;
    const bool s1ok = (m0 + s1) < N_PTS;
    const int r0c = (m0 + s0) < N_PTS ? (m0 + s0) : (N_PTS - 1);  // clamped load rows
    const int r1c = (m0 + s1) < N_PTS ? (m0 + s1) : (N_PTS - 1);
    const int aswz = (lu ^ (s0 & 7)) << 4;    // s1&7 == s0&7

    const char* dbfB = (const char*)dbf;
    const char* wkhB = (const char*)wkh;
    char* pAr = (char*)lds;                    // A read (phase p)
    char* pAm = (char*)lds + 16384;            // A mid  (phase p+1)
    char* pAw = (char*)lds + 32768;            // A write (phase p+2)
    char* pBr = (char*)lds + 49152;            // B read
    char* pBw = (char*)lds + 65536;            // B write

    facc4 acc[2][4];
    const facc4 fz = {0.f, 0.f, 0.f, 0.f};
#pragma unroll
    for (int a = 0; a < 2; ++a)
#pragma unroll
        for (int b = 0; b < 4; ++b) acc[a][b] = fz;

    // ---- prologue: iv gens 0..2; A(0),B(0),A(1); leave A(1) in flight ----
    int ivA0, ivA1, ivB0, ivB1, ivc0, ivc1, ivn0, ivn1;
    LOAD_IV(0, ivA0, ivA1)
    LOAD_IV(1, ivB0, ivB1)
    LOAD_IV(2, ivc0, ivc1)
    STAGE_A(0, pAr, ivA0, ivA1)
    STAGE_B(0, pBr)
    STAGE_A(1, pAm, ivB0, ivB1)
    WAIT_BAR(2)

    // ---- phases 0..50 uniform: {B(p+1); A(p+2); MFMA(p); iv(p+3); vmcnt(4)} ----
#pragma unroll 1
    for (int p = 0; p <= 50; ++p) {
        STAGE_B(p + 1, pBw)
        STAGE_A(p + 2, pAw, ivc0, ivc1)
        MFMA_PHASE(pAr, pBr)
        LOAD_IV(p + 3, ivn0, ivn1)
        WAIT_BAR(4)
        ROTATE_BUFS
        ivc0 = ivn0; ivc1 = ivn1;
    }
    // ---- phase 51: B(52); A(53); MFMA; vmcnt(2) ----
    STAGE_B(52, pBw)
    STAGE_A(53, pAw, ivc0, ivc1)
    MFMA_PHASE(pAr, pBr)
    WAIT_BAR(2)
    ROTATE_BUFS
    // ---- phase 52: B(53); MFMA; drain ----
    STAGE_B(53, pBw)
    MFMA_PHASE(pAr, pBr)
    WAIT_BAR(0)
    ROTATE_BUFS
    // ---- phase 53: compute only ----
    MFMA_PHASE(pAr, pBr)

    // ---- epilogue: C/D col=lane&15, row=(lane>>4)*4+reg ----
#pragma unroll
    for (int rt = 0; rt < 2; ++rt) {
        const int r0 = m0 + wrow * 32 + rt * 16 + lk * 4;
#pragma unroll
        for (int ct = 0; ct < 4; ++ct) {
#pragma unroll
            for (int r = 0; r < 4; ++r) {
                int row = r0 + r;
                if (row < N_PTS)
                    out[(size_t)row * COUT + h * 64 + ct * 16 + lr] = acc[rt][ct][r];
            }
        }
    }
}

// ---- emergency fallback ----
__global__ void naive_kernel(const float* __restrict__ data, const float* __restrict__ wgt,
                             const int* __restrict__ nbr, float* __restrict__ out) {
    int mm = blockIdx.x;
    int co = threadIdx.x;
    if (mm >= N_PTS) return;
    float acc = 0.f;
    for (int k = 0; k < NK; ++k) {
        int idx = nbr[mm * NK + k];
        if (idx < 0) continue;
        const float* d  = data + (size_t)idx * CIN;
        const float* wp = wgt + ((size_t)co * NK + k) * CIN;
        for (int ci = 0; ci < CIN; ++ci) acc += d[ci] * wp[ci];
    }
    out[(size_t)mm * COUT + co] = acc;
}

extern "C" void kernel_launch(void* const* d_in, const int* in_sizes, int n_in,
                              void* d_out, int out_size, void* d_ws, size_t ws_size,
                              hipStream_t stream) {
    const float* data = (const float*)d_in[0];
    const float* wgt  = (const float*)d_in[1];
    const int*   nbr  = (const int*)d_in[2];
    float*       out  = (float*)d_out;

    const size_t wk_bytes   = (size_t)NK * 2 * 128 * 8 * 16;      // 884,736
    const size_t dbf_bytes  = (size_t)(N_PTS + 1) * CIN * 2;      // 38,400,256
    const size_t nbrT_bytes = (size_t)NK * N_PTS * 4;             // 16,200,000

    if (ws_size < wk_bytes + dbf_bytes) {
        naive_kernel<<<N_PTS, COUT, 0, stream>>>(data, wgt, nbr, out);
        return;
    }
    unsigned short* wkh = (unsigned short*)d_ws;
    unsigned short* dbf = (unsigned short*)((char*)d_ws + wk_bytes);

    prep_weights_h<<<(NK * 2 * 128 * 8 + 255) / 256, 256, 0, stream>>>(wgt, wkh);
    cast_data_kernel<<<2048, 256, 0, stream>>>(data, dbf);

    if (ws_size >= wk_bytes + dbf_bytes + nbrT_bytes) {
        int* nbrT = (int*)((char*)d_ws + wk_bytes + dbf_bytes);   // 256B-aligned
        transpose_nbr<<<(N_PTS + 255) / 256, 256, 0, stream>>>(nbr, nbrT);
        octconv_v11<<<NBLK, 512, 0, stream>>>(dbf, wkh, nbrT, N_PTS, 1, out);
    } else {
        octconv_v11<<<NBLK, 512, 0, stream>>>(dbf, wkh, nbr, 1, NK, out);
    }
}